// Round 12
// baseline (239.382 us; speedup 1.0000x reference)
//
#include <hip/hip_runtime.h>
#include <hip/hip_bf16.h>

#define DD 128
#define TM 64
#define LD 136        // padded LDS row stride (bf16 elems)
#define SB 128        // scan blocks
#define GRID_MLP 1024 // 4 blocks/CU persistent

typedef short bf16x8 __attribute__((ext_vector_type(8)));
typedef float f32x4  __attribute__((ext_vector_type(4)));

__device__ __forceinline__ unsigned short f2bf(float f) {
  unsigned int u = __float_as_uint(f);
  u += 0x7FFFu + ((u >> 16) & 1u);   // RNE
  return (unsigned short)(u >> 16);
}
__device__ __forceinline__ unsigned int pack2(float lo, float hi) {
  return (unsigned int)f2bf(lo) | ((unsigned int)f2bf(hi) << 16);
}
__device__ __forceinline__ float bf2f(unsigned short u) {
  union { unsigned int i; float f; } x; x.i = ((unsigned int)u) << 16; return x.f;
}
// unpack one dword (2 bf16) to two fp32 and add into a[2]
__device__ __forceinline__ void add2(float* a, unsigned int w) {
  union { unsigned int i; float f; } lo, hi;
  lo.i = w << 16; hi.i = w & 0xFFFF0000u;
  a[0] += lo.f; a[1] += hi.f;
}

// init: zero cnt, convert weights AND features fp32->bf16. One dispatch.
__global__ __launch_bounds__(256) void k_init(const float* __restrict__ w1,
                                              const float* __restrict__ w2,
                                              const float* __restrict__ feat,
                                              unsigned short* __restrict__ wbf1,
                                              unsigned short* __restrict__ wbf2,
                                              unsigned short* __restrict__ featbf,
                                              int* __restrict__ cnt, int nrows) {
  int i0 = blockIdx.x * 256 + threadIdx.x;
  int GT = gridDim.x * 256;
  for (int i = i0; i < nrows; i += GT) cnt[i] = 0;
  for (int i = i0; i < DD * DD; i += GT) { wbf1[i] = f2bf(w1[i]); wbf2[i] = f2bf(w2[i]); }
  int total8 = nrows * 16;   // 8 elems per thread
  for (int i = i0; i < total8; i += GT) {
    const float* fp = feat + (long long)i * 8;
    float4 a = *reinterpret_cast<const float4*>(fp);
    float4 b = *reinterpret_cast<const float4*>(fp + 4);
    uint4 u;
    u.x = pack2(a.x, a.y); u.y = pack2(a.z, a.w);
    u.z = pack2(b.x, b.y); u.w = pack2(b.z, b.w);
    *reinterpret_cast<uint4*>(featbf + (long long)i * 8) = u;
  }
}

// cnt[dst]++ per edge (int atomics, L2-resident)
__global__ __launch_bounds__(256) void k_hist(const int* __restrict__ ei, int* __restrict__ cnt,
                                              int ne) {
  int e = blockIdx.x * 256 + threadIdx.x;
  if (e < ne) atomicAdd(&cnt[ei[ne + e]], 1);
}

// Merged single-dispatch scan (R10 retry, R10-bug fixed): each block computes
// its prefix base = sum cnt[0..blo) with 8 INDEPENDENT accumulators (8 loads
// in flight per thread -> L2 latency pipelined; R10's serial `s+=cnt[i]` chain
// was 300cy/elem), then exclusive-scans its own chunk -> ofs, cur.
__global__ __launch_bounds__(256) void k_scan(const int* __restrict__ cnt,
                                              int* __restrict__ ofs, int* __restrict__ cur,
                                              int n) {
  __shared__ int red[256];
  __shared__ int sbase;
  int b = blockIdx.x, t = threadIdx.x;
  int chunk = (n + SB - 1) / SB;
  int blo = b * chunk, bhi = min(n, blo + chunk);

  // base = sum cnt[0..blo), 8-way unrolled independent accumulators
  int s0 = 0, s1 = 0, s2 = 0, s3 = 0, s4 = 0, s5 = 0, s6 = 0, s7 = 0;
  int i = t;
  for (; i + 7 * 256 < blo; i += 8 * 256) {
    s0 += cnt[i];
    s1 += cnt[i + 256];
    s2 += cnt[i + 512];
    s3 += cnt[i + 768];
    s4 += cnt[i + 1024];
    s5 += cnt[i + 1280];
    s6 += cnt[i + 1536];
    s7 += cnt[i + 1792];
  }
  for (; i < blo; i += 256) s0 += cnt[i];
  int s = ((s0 + s1) + (s2 + s3)) + ((s4 + s5) + (s6 + s7));
  red[t] = s;
  __syncthreads();
  for (int off = 128; off; off >>= 1) {
    if (t < off) red[t] += red[t + off];
    __syncthreads();
  }
  if (t == 0) sbase = red[0];
  __syncthreads();
  int base = sbase;
  __syncthreads();   // red reused below

  // exclusive scan of own chunk
  int tchunk = (chunk + 255) / 256;
  int lo = blo + t * tchunk, hi = min(bhi, lo + tchunk);
  s = 0;
  for (int j = lo; j < hi; ++j) s += cnt[j];
  int mine = s;
  red[t] = s;
  __syncthreads();
  for (int off = 1; off < 256; off <<= 1) {
    int v = (t >= off) ? red[t - off] : 0;
    __syncthreads();
    red[t] += v;
    __syncthreads();
  }
  int run = base + red[t] - mine;
  for (int j = lo; j < hi; ++j) {
    int c = cnt[j];
    ofs[j] = run; cur[j] = run;
    run += c;
  }
  if (b == SB - 1 && t == 255) ofs[n] = base + red[255];
}

// csr[pos] = src, pos = cur[dst]++
__global__ __launch_bounds__(256) void k_fill(const int* __restrict__ ei, int* __restrict__ cur,
                                              int* __restrict__ csr, int ne) {
  int e = blockIdx.x * 256 + threadIdx.x;
  if (e >= ne) return;
  int pos = atomicAdd(&cur[ei[ne + e]], 1);
  csr[pos] = ei[e];
}

// Gather from bf16 features (256 B/row): h = feat[row] + sum(neighbors).
// fp32 accumulation of bf16-rounded inputs; RNE-pack to bf16 agg (== hbuf).
__global__ __launch_bounds__(256) void k_agg(
    const unsigned short* __restrict__ featbf, const int* __restrict__ ofs,
    const int* __restrict__ csr, unsigned short* __restrict__ agg, int nrows)
{
  int t = blockIdx.x * 256 + threadIdx.x;   // 16 threads per row, 8 cols each
  int row = t >> 4;
  if (row >= nrows) return;
  int c = (t & 15) * 8;

  float a[8];
  {
    uint4 u = *reinterpret_cast<const uint4*>(featbf + (long long)row * DD + c);
    union { unsigned int i; float f; } x;
    x.i = u.x << 16; a[0] = x.f;  x.i = u.x & 0xFFFF0000u; a[1] = x.f;
    x.i = u.y << 16; a[2] = x.f;  x.i = u.y & 0xFFFF0000u; a[3] = x.f;
    x.i = u.z << 16; a[4] = x.f;  x.i = u.z & 0xFFFF0000u; a[5] = x.f;
    x.i = u.w << 16; a[6] = x.f;  x.i = u.w & 0xFFFF0000u; a[7] = x.f;
  }

  int o0 = ofs[row], o1 = ofs[row + 1];
  int j = o0;
  for (; j + 4 <= o1; j += 4) {
    uint4 u0 = *reinterpret_cast<const uint4*>(featbf + (long long)csr[j]     * DD + c);
    uint4 u1 = *reinterpret_cast<const uint4*>(featbf + (long long)csr[j + 1] * DD + c);
    uint4 u2 = *reinterpret_cast<const uint4*>(featbf + (long long)csr[j + 2] * DD + c);
    uint4 u3 = *reinterpret_cast<const uint4*>(featbf + (long long)csr[j + 3] * DD + c);
    add2(a + 0, u0.x); add2(a + 2, u0.y); add2(a + 4, u0.z); add2(a + 6, u0.w);
    add2(a + 0, u1.x); add2(a + 2, u1.y); add2(a + 4, u1.z); add2(a + 6, u1.w);
    add2(a + 0, u2.x); add2(a + 2, u2.y); add2(a + 4, u2.z); add2(a + 6, u2.w);
    add2(a + 0, u3.x); add2(a + 2, u3.y); add2(a + 4, u3.z); add2(a + 6, u3.w);
  }
  for (; j < o1; ++j) {
    uint4 u0 = *reinterpret_cast<const uint4*>(featbf + (long long)csr[j] * DD + c);
    add2(a + 0, u0.x); add2(a + 2, u0.y); add2(a + 4, u0.z); add2(a + 6, u0.w);
  }

  uint4 u;
  u.x = pack2(a[0], a[1]); u.y = pack2(a[2], a[3]);
  u.z = pack2(a[4], a[5]); u.w = pack2(a[6], a[7]);
  *reinterpret_cast<uint4*>(agg + (long long)row * DD + c) = u;
}

// Persistent fused MLP, SWAPPED-OPERAND MFMA (verified R10/R11): mfma(W, x)
// puts 4 consecutive output columns of one row in each lane's C-regs ->
// h2/epilogue packs are 8B ds-writes. A-loads direct from global (row-major
// bf16 hbuf == fragment layout). BN stats register-accumulated per block.
__global__ __launch_bounds__(256) void k_mlp(
    unsigned short* hb,
    const unsigned short* __restrict__ wbf1, const float* __restrict__ b1,
    const unsigned short* __restrict__ wbf2, const float* __restrict__ b2,
    float* __restrict__ partial, int nrows, int ntiles)
{
  __shared__ unsigned short ldsP[TM * LD];   // epilogue pack buffer
  __shared__ unsigned short ldsH2[TM * LD];  // h2 buffer
  const int tid  = threadIdx.x;
  const int wave = tid >> 6, lane = tid & 63;
  const int q = lane >> 4, l16 = lane & 15;
  const int col0 = wave * 32;

  bf16x8 bw1[2][4], bw2[2][4];
  for (int n = 0; n < 2; ++n) {
    int jc = col0 + n * 16 + l16;
    for (int kk = 0; kk < 4; ++kk) {
      bw1[n][kk] = *reinterpret_cast<const bf16x8*>(wbf1 + jc * DD + kk * 32 + q * 8);
      bw2[n][kk] = *reinterpret_cast<const bf16x8*>(wbf2 + jc * DD + kk * 32 + q * 8);
    }
  }
  float bias1v[2][4], bias2v[2][4];
  for (int n = 0; n < 2; ++n)
    for (int r = 0; r < 4; ++r) {
      int jc = col0 + n * 16 + q * 4 + r;
      bias1v[n][r] = b1[jc];
      bias2v[n][r] = b2[jc];
    }

  const bf16x8 zf = {0, 0, 0, 0, 0, 0, 0, 0};
  float fs[2][4] = {{0.f,0.f,0.f,0.f},{0.f,0.f,0.f,0.f}};
  float fs2[2][4] = {{0.f,0.f,0.f,0.f},{0.f,0.f,0.f,0.f}};

  for (int tile = blockIdx.x; tile < ntiles; tile += GRID_MLP) {
    const int row0 = tile * TM;

    f32x4 acc[4][2];
    const f32x4 zero = {0.f, 0.f, 0.f, 0.f};
    for (int m = 0; m < 4; ++m) for (int n = 0; n < 2; ++n) acc[m][n] = zero;

    // GEMM1: x-fragments straight from global (B operand).
    #pragma unroll
    for (int kk = 0; kk < 4; ++kk) {
      bf16x8 aF[4];
      #pragma unroll
      for (int m = 0; m < 4; ++m) {
        int row = row0 + m * 16 + l16;
        aF[m] = (row < nrows)
            ? *reinterpret_cast<const bf16x8*>(hb + (long long)row * DD + kk * 32 + q * 8)
            : zf;
      }
      #pragma unroll
      for (int m = 0; m < 4; ++m)
        #pragma unroll
        for (int n = 0; n < 2; ++n)
          acc[m][n] = __builtin_amdgcn_mfma_f32_16x16x32_bf16(bw1[n][kk], aF[m], acc[m][n], 0, 0, 0);
    }

    // h2 = relu(acc + b1) -> ldsH2: one 8B write per (m,n).
    #pragma unroll
    for (int m = 0; m < 4; ++m)
      #pragma unroll
      for (int n = 0; n < 2; ++n) {
        float v0 = fmaxf(acc[m][n][0] + bias1v[n][0], 0.f);
        float v1 = fmaxf(acc[m][n][1] + bias1v[n][1], 0.f);
        float v2 = fmaxf(acc[m][n][2] + bias1v[n][2], 0.f);
        float v3 = fmaxf(acc[m][n][3] + bias1v[n][3], 0.f);
        uint2 w;
        w.x = pack2(v0, v1);
        w.y = pack2(v2, v3);
        *reinterpret_cast<uint2*>(&ldsH2[(m * 16 + l16) * LD + col0 + n * 16 + q * 4]) = w;
      }
    __syncthreads();   // S1

    for (int m = 0; m < 4; ++m) for (int n = 0; n < 2; ++n) acc[m][n] = zero;

    // GEMM2 from LDS.
    #pragma unroll
    for (int kk = 0; kk < 4; ++kk) {
      bf16x8 aF[4];
      #pragma unroll
      for (int m = 0; m < 4; ++m)
        aF[m] = *reinterpret_cast<const bf16x8*>(&ldsH2[(m * 16 + l16) * LD + kk * 32 + q * 8]);
      #pragma unroll
      for (int m = 0; m < 4; ++m)
        #pragma unroll
        for (int n = 0; n < 2; ++n)
          acc[m][n] = __builtin_amdgcn_mfma_f32_16x16x32_bf16(bw2[n][kk], aF[m], acc[m][n], 0, 0, 0);
    }

    // Epilogue: relu+bias, BN stats in regs, pack -> ldsP (8B writes).
    #pragma unroll
    for (int m = 0; m < 4; ++m) {
      bool rowok = (row0 + m * 16 + l16) < nrows;
      #pragma unroll
      for (int n = 0; n < 2; ++n) {
        float v0 = fmaxf(acc[m][n][0] + bias2v[n][0], 0.f);
        float v1 = fmaxf(acc[m][n][1] + bias2v[n][1], 0.f);
        float v2 = fmaxf(acc[m][n][2] + bias2v[n][2], 0.f);
        float v3 = fmaxf(acc[m][n][3] + bias2v[n][3], 0.f);
        if (rowok) {
          fs[n][0] += v0; fs2[n][0] += v0 * v0;
          fs[n][1] += v1; fs2[n][1] += v1 * v1;
          fs[n][2] += v2; fs2[n][2] += v2 * v2;
          fs[n][3] += v3; fs2[n][3] += v3 * v3;
        }
        uint2 w;
        w.x = pack2(v0, v1);
        w.y = pack2(v2, v3);
        *reinterpret_cast<uint2*>(&ldsP[(m * 16 + l16) * LD + col0 + n * 16 + q * 4]) = w;
      }
    }
    __syncthreads();   // S2

    for (int it = 0; it < 4; ++it) {
      int idx = it * 2048 + tid * 8;
      int r = idx >> 7, c = idx & 127;
      int row = row0 + r;
      if (row < nrows)
        *reinterpret_cast<uint4*>(hb + (long long)row * DD + c) =
            *reinterpret_cast<const uint4*>(&ldsP[r * LD + c]);
    }
  }

  // Stats reduce across the 16 l16-lanes; l16==0 lanes write 8 cols each.
  for (int off = 1; off < 16; off <<= 1)
    for (int n = 0; n < 2; ++n)
      for (int r = 0; r < 4; ++r) {
        fs[n][r]  += __shfl_xor(fs[n][r], off);
        fs2[n][r] += __shfl_xor(fs2[n][r], off);
      }
  if (l16 == 0) {
    float* pb = partial + (long long)blockIdx.x * 256;
    for (int n = 0; n < 2; ++n)
      for (int r = 0; r < 4; ++r) {
        int col = col0 + n * 16 + q * 4 + r;
        pb[col]       = fs[n][r];
        pb[128 + col] = fs2[n][r];
      }
  }
}

// Reduce per-block partials -> scale/shift. 128 blocks: block c owns cols (c, 128+c).
__global__ __launch_bounds__(256) void k_stats(const float* __restrict__ partial,
                                               const float* __restrict__ gamma,
                                               const float* __restrict__ beta,
                                               float* __restrict__ scsh, int nrows) {
  __shared__ float s0[256], s1[256];
  int c = blockIdx.x;   // 0..127
  int t = threadIdx.x;
  float a = 0.f, b = 0.f;
  for (int r = t; r < GRID_MLP; r += 256) {
    a += partial[(long long)r * 256 + c];
    b += partial[(long long)r * 256 + 128 + c];
  }
  s0[t] = a; s1[t] = b;
  __syncthreads();
  for (int off = 128; off; off >>= 1) {
    if (t < off) { s0[t] += s0[t + off]; s1[t] += s1[t + off]; }
    __syncthreads();
  }
  if (t == 0) {
    float mean = s0[0] / (float)nrows;
    float var  = fmaxf(s1[0] / (float)nrows - mean * mean, 0.f);
    float inv  = rsqrtf(var + 1e-5f);
    float sc   = gamma[c] * inv;
    scsh[c]       = sc;
    scsh[128 + c] = beta[c] - mean * sc;
  }
}

// BN apply: read bf16 hbuf (L3-warm), write fp32 out. One thread per 8 elems.
__global__ __launch_bounds__(256) void k_bn(const unsigned short* __restrict__ hbuf,
                                            float* __restrict__ out,
                                            const float* __restrict__ scsh,
                                            long long total8) {
  long long t = (long long)blockIdx.x * 256 + threadIdx.x;
  if (t >= total8) return;
  int c0 = (int)((t * 8) & 127);
  float4 sa = *reinterpret_cast<const float4*>(scsh + c0);
  float4 sb = *reinterpret_cast<const float4*>(scsh + c0 + 4);
  float4 ha = *reinterpret_cast<const float4*>(scsh + 128 + c0);
  float4 hb = *reinterpret_cast<const float4*>(scsh + 132 + c0);
  uint4 u = *reinterpret_cast<const uint4*>(hbuf + t * 8);
  float4 a, b;
  a.x = bf2f((unsigned short)(u.x & 0xFFFF)) * sa.x + ha.x;
  a.y = bf2f((unsigned short)(u.x >> 16))    * sa.y + ha.y;
  a.z = bf2f((unsigned short)(u.y & 0xFFFF)) * sa.z + ha.z;
  a.w = bf2f((unsigned short)(u.y >> 16))    * sa.w + ha.w;
  b.x = bf2f((unsigned short)(u.z & 0xFFFF)) * sb.x + hb.x;
  b.y = bf2f((unsigned short)(u.z >> 16))    * sb.y + hb.y;
  b.z = bf2f((unsigned short)(u.w & 0xFFFF)) * sb.z + hb.z;
  b.w = bf2f((unsigned short)(u.w >> 16))    * sb.w + hb.w;
  float* of = out + t * 8;
  *reinterpret_cast<float4*>(of)     = a;
  *reinterpret_cast<float4*>(of + 4) = b;
}

extern "C" void kernel_launch(void* const* d_in, const int* in_sizes, int n_in,
                              void* d_out, int out_size, void* d_ws, size_t ws_size,
                              hipStream_t stream) {
  const float* feat  = (const float*)d_in[0];
  const int*   eidx  = (const int*)d_in[1];
  const float* w1    = (const float*)d_in[2];
  const float* b1    = (const float*)d_in[3];
  const float* w2    = (const float*)d_in[4];
  const float* b2    = (const float*)d_in[5];
  const float* gamma = (const float*)d_in[6];
  const float* beta  = (const float*)d_in[7];
  float* out = (float*)d_out;

  const int nrows  = in_sizes[0] / DD;       // 100000
  const int ne     = in_sizes[1] / 2;        // 400000
  const int ntiles = (nrows + TM - 1) / TM;  // 1563

  // ws layout (4B words), featbf + hbuf last (16B-aligned by construction):
  int* base = (int*)d_ws;
  unsigned short* wbf1 = (unsigned short*)base;            // 16384 bf16
  unsigned short* wbf2 = (unsigned short*)(base + 8192);   // 16384 bf16
  float* scsh  = (float*)(base + 16384);                   // 256
  int*   ofs   = base + 16384 + 256;                       // nrows+1
  int*   cur   = ofs + (nrows + 1);
  int*   csr   = cur + nrows;
  float* partial = (float*)(csr + ne);                     // GRID_MLP*256 (1 MB)
  int*   cnt   = (int*)(partial + (size_t)GRID_MLP * 256); // nrows
  long long w_off = (long long)(cnt + nrows - base);
  w_off = (w_off + 3) & ~3LL;                              // 16B align
  unsigned short* featbf = (unsigned short*)(base + w_off);       // nrows*DD bf16 (25.6 MB)
  unsigned short* hbuf   = featbf + (long long)nrows * DD;        // nrows*DD bf16 (25.6 MB)

  const long long total8 = (long long)nrows * DD / 8;      // 1.6M
  const int agg_blocks  = (nrows * 16 + 255) / 256;        // 6250

  k_init <<<2048,                         256, 0, stream>>>(w1, w2, feat, wbf1, wbf2,
                                                            featbf, cnt, nrows);
  k_hist <<<(ne + 255) / 256,             256, 0, stream>>>(eidx, cnt, ne);
  k_scan <<<SB,                           256, 0, stream>>>(cnt, ofs, cur, nrows);
  k_fill <<<(ne + 255) / 256,             256, 0, stream>>>(eidx, cur, csr, ne);
  k_agg  <<<agg_blocks,                   256, 0, stream>>>(featbf, ofs, csr, hbuf, nrows);
  k_mlp  <<<GRID_MLP,                     256, 0, stream>>>(hbuf, wbf1, b1, wbf2, b2,
                                                            partial, nrows, ntiles);
  k_stats<<<128,                          256, 0, stream>>>(partial, gamma, beta, scsh, nrows);
  k_bn   <<<(int)((total8 + 255) / 256),  256, 0, stream>>>(hbuf, out, scsh, total8);
}

// Round 13
// 238.281 us; speedup vs baseline: 1.0046x; 1.0046x over previous
//
#include <hip/hip_runtime.h>
#include <hip/hip_bf16.h>

#define DD 128
#define TM 64
#define LD 136        // padded LDS row stride (bf16 elems)
#define SB 128        // scan blocks
#define GRID_MLP 1024 // 4 blocks/CU persistent

typedef short bf16x8 __attribute__((ext_vector_type(8)));
typedef float f32x4  __attribute__((ext_vector_type(4)));

__device__ __forceinline__ unsigned short f2bf(float f) {
  unsigned int u = __float_as_uint(f);
  u += 0x7FFFu + ((u >> 16) & 1u);   // RNE
  return (unsigned short)(u >> 16);
}
__device__ __forceinline__ unsigned int pack2(float lo, float hi) {
  return (unsigned int)f2bf(lo) | ((unsigned int)f2bf(hi) << 16);
}
__device__ __forceinline__ float bf2f(unsigned short u) {
  union { unsigned int i; float f; } x; x.i = ((unsigned int)u) << 16; return x.f;
}
// unpack one dword (2 bf16) to two fp32 and add into a[2]
__device__ __forceinline__ void add2(float* a, unsigned int w) {
  union { unsigned int i; float f; } lo, hi;
  lo.i = w << 16; hi.i = w & 0xFFFF0000u;
  a[0] += lo.f; a[1] += hi.f;
}

// init: zero cnt, convert weights AND features fp32->bf16. One dispatch.
__global__ __launch_bounds__(256) void k_init(const float* __restrict__ w1,
                                              const float* __restrict__ w2,
                                              const float* __restrict__ feat,
                                              unsigned short* __restrict__ wbf1,
                                              unsigned short* __restrict__ wbf2,
                                              unsigned short* __restrict__ featbf,
                                              int* __restrict__ cnt, int nrows) {
  int i0 = blockIdx.x * 256 + threadIdx.x;
  int GT = gridDim.x * 256;
  for (int i = i0; i < nrows; i += GT) cnt[i] = 0;
  for (int i = i0; i < DD * DD; i += GT) { wbf1[i] = f2bf(w1[i]); wbf2[i] = f2bf(w2[i]); }
  int total8 = nrows * 16;   // 8 elems per thread
  for (int i = i0; i < total8; i += GT) {
    const float* fp = feat + (long long)i * 8;
    float4 a = *reinterpret_cast<const float4*>(fp);
    float4 b = *reinterpret_cast<const float4*>(fp + 4);
    uint4 u;
    u.x = pack2(a.x, a.y); u.y = pack2(a.z, a.w);
    u.z = pack2(b.x, b.y); u.w = pack2(b.z, b.w);
    *reinterpret_cast<uint4*>(featbf + (long long)i * 8) = u;
  }
}

// cnt[dst]++ per edge (int atomics, L2-resident)
__global__ __launch_bounds__(256) void k_hist(const int* __restrict__ ei, int* __restrict__ cnt,
                                              int ne) {
  int e = blockIdx.x * 256 + threadIdx.x;
  if (e < ne) atomicAdd(&cnt[ei[ne + e]], 1);
}

// Merged single-dispatch scan (verified R12): each block computes its prefix
// base = sum cnt[0..blo) with 8 independent accumulators (loads pipelined;
// R10's serial chain was the failure), then exclusive-scans its chunk.
__global__ __launch_bounds__(256) void k_scan(const int* __restrict__ cnt,
                                              int* __restrict__ ofs, int* __restrict__ cur,
                                              int n) {
  __shared__ int red[256];
  __shared__ int sbase;
  int b = blockIdx.x, t = threadIdx.x;
  int chunk = (n + SB - 1) / SB;
  int blo = b * chunk, bhi = min(n, blo + chunk);

  int s0 = 0, s1 = 0, s2 = 0, s3 = 0, s4 = 0, s5 = 0, s6 = 0, s7 = 0;
  int i = t;
  for (; i + 7 * 256 < blo; i += 8 * 256) {
    s0 += cnt[i];
    s1 += cnt[i + 256];
    s2 += cnt[i + 512];
    s3 += cnt[i + 768];
    s4 += cnt[i + 1024];
    s5 += cnt[i + 1280];
    s6 += cnt[i + 1536];
    s7 += cnt[i + 1792];
  }
  for (; i < blo; i += 256) s0 += cnt[i];
  int s = ((s0 + s1) + (s2 + s3)) + ((s4 + s5) + (s6 + s7));
  red[t] = s;
  __syncthreads();
  for (int off = 128; off; off >>= 1) {
    if (t < off) red[t] += red[t + off];
    __syncthreads();
  }
  if (t == 0) sbase = red[0];
  __syncthreads();
  int base = sbase;
  __syncthreads();   // red reused below

  int tchunk = (chunk + 255) / 256;
  int lo = blo + t * tchunk, hi = min(bhi, lo + tchunk);
  s = 0;
  for (int j = lo; j < hi; ++j) s += cnt[j];
  int mine = s;
  red[t] = s;
  __syncthreads();
  for (int off = 1; off < 256; off <<= 1) {
    int v = (t >= off) ? red[t - off] : 0;
    __syncthreads();
    red[t] += v;
    __syncthreads();
  }
  int run = base + red[t] - mine;
  for (int j = lo; j < hi; ++j) {
    int c = cnt[j];
    ofs[j] = run; cur[j] = run;
    run += c;
  }
  if (b == SB - 1 && t == 255) ofs[n] = base + red[255];
}

// csr[pos] = src, pos = cur[dst]++
__global__ __launch_bounds__(256) void k_fill(const int* __restrict__ ei, int* __restrict__ cur,
                                              int* __restrict__ csr, int ne) {
  int e = blockIdx.x * 256 + threadIdx.x;
  if (e >= ne) return;
  int pos = atomicAdd(&cur[ei[ne + e]], 1);
  csr[pos] = ei[e];
}

// Gather from bf16 features (256 B/row): h = feat[row] + sum(neighbors).
// fp32 accumulation of bf16-rounded inputs; RNE-pack to bf16 agg (== hbuf).
__global__ __launch_bounds__(256) void k_agg(
    const unsigned short* __restrict__ featbf, const int* __restrict__ ofs,
    const int* __restrict__ csr, unsigned short* __restrict__ agg, int nrows)
{
  int t = blockIdx.x * 256 + threadIdx.x;   // 16 threads per row, 8 cols each
  int row = t >> 4;
  if (row >= nrows) return;
  int c = (t & 15) * 8;

  float a[8];
  {
    uint4 u = *reinterpret_cast<const uint4*>(featbf + (long long)row * DD + c);
    union { unsigned int i; float f; } x;
    x.i = u.x << 16; a[0] = x.f;  x.i = u.x & 0xFFFF0000u; a[1] = x.f;
    x.i = u.y << 16; a[2] = x.f;  x.i = u.y & 0xFFFF0000u; a[3] = x.f;
    x.i = u.z << 16; a[4] = x.f;  x.i = u.z & 0xFFFF0000u; a[5] = x.f;
    x.i = u.w << 16; a[6] = x.f;  x.i = u.w & 0xFFFF0000u; a[7] = x.f;
  }

  int o0 = ofs[row], o1 = ofs[row + 1];
  int j = o0;
  for (; j + 4 <= o1; j += 4) {
    uint4 u0 = *reinterpret_cast<const uint4*>(featbf + (long long)csr[j]     * DD + c);
    uint4 u1 = *reinterpret_cast<const uint4*>(featbf + (long long)csr[j + 1] * DD + c);
    uint4 u2 = *reinterpret_cast<const uint4*>(featbf + (long long)csr[j + 2] * DD + c);
    uint4 u3 = *reinterpret_cast<const uint4*>(featbf + (long long)csr[j + 3] * DD + c);
    add2(a + 0, u0.x); add2(a + 2, u0.y); add2(a + 4, u0.z); add2(a + 6, u0.w);
    add2(a + 0, u1.x); add2(a + 2, u1.y); add2(a + 4, u1.z); add2(a + 6, u1.w);
    add2(a + 0, u2.x); add2(a + 2, u2.y); add2(a + 4, u2.z); add2(a + 6, u2.w);
    add2(a + 0, u3.x); add2(a + 2, u3.y); add2(a + 4, u3.z); add2(a + 6, u3.w);
  }
  for (; j < o1; ++j) {
    uint4 u0 = *reinterpret_cast<const uint4*>(featbf + (long long)csr[j] * DD + c);
    add2(a + 0, u0.x); add2(a + 2, u0.y); add2(a + 4, u0.z); add2(a + 6, u0.w);
  }

  uint4 u;
  u.x = pack2(a[0], a[1]); u.y = pack2(a[2], a[3]);
  u.z = pack2(a[4], a[5]); u.w = pack2(a[6], a[7]);
  *reinterpret_cast<uint4*>(agg + (long long)row * DD + c) = u;
}

// Persistent fused MLP (R9/R7 variant — the best-measured one; R10's swapped
// operands reverted: R11/R12 showed neutral-to-negative). Row-major bf16 hbuf
// == MFMA A-fragment layout -> GEMM1 loads A directly from global. h2 transits
// LDS; epilogue packs via LDS for coalesced stores. BN stats in registers.
__global__ __launch_bounds__(256) void k_mlp(
    unsigned short* hb,
    const unsigned short* __restrict__ wbf1, const float* __restrict__ b1,
    const unsigned short* __restrict__ wbf2, const float* __restrict__ b2,
    float* __restrict__ partial, int nrows, int ntiles)
{
  __shared__ unsigned short ldsP[TM * LD];   // epilogue pack buffer
  __shared__ unsigned short ldsH2[TM * LD];  // h2 buffer
  const int tid  = threadIdx.x;
  const int wave = tid >> 6, lane = tid & 63;
  const int q = lane >> 4, l16 = lane & 15;
  const int col0 = wave * 32;

  bf16x8 bw1[2][4], bw2[2][4];
  float bias1[2], bias2[2];
  for (int n = 0; n < 2; ++n) {
    int jc = col0 + n * 16 + l16;
    bias1[n] = b1[jc];
    bias2[n] = b2[jc];
    for (int kk = 0; kk < 4; ++kk) {
      bw1[n][kk] = *reinterpret_cast<const bf16x8*>(wbf1 + jc * DD + kk * 32 + q * 8);
      bw2[n][kk] = *reinterpret_cast<const bf16x8*>(wbf2 + jc * DD + kk * 32 + q * 8);
    }
  }

  const bf16x8 zf = {0, 0, 0, 0, 0, 0, 0, 0};
  float fs[2] = {0.f, 0.f}, fs2[2] = {0.f, 0.f};

  for (int tile = blockIdx.x; tile < ntiles; tile += GRID_MLP) {
    const int row0 = tile * TM;

    f32x4 acc[4][2];
    const f32x4 zero = {0.f, 0.f, 0.f, 0.f};
    for (int m = 0; m < 4; ++m) for (int n = 0; n < 2; ++n) acc[m][n] = zero;

    // GEMM1: A-fragments straight from global (row-major == fragment layout).
    #pragma unroll
    for (int kk = 0; kk < 4; ++kk) {
      bf16x8 aF[4];
      #pragma unroll
      for (int m = 0; m < 4; ++m) {
        int row = row0 + m * 16 + l16;
        aF[m] = (row < nrows)
            ? *reinterpret_cast<const bf16x8*>(hb + (long long)row * DD + kk * 32 + q * 8)
            : zf;
      }
      #pragma unroll
      for (int m = 0; m < 4; ++m)
        #pragma unroll
        for (int n = 0; n < 2; ++n)
          acc[m][n] = __builtin_amdgcn_mfma_f32_16x16x32_bf16(aF[m], bw1[n][kk], acc[m][n], 0, 0, 0);
    }

    // h2 = relu(acc + b1) -> ldsH2 (C/D: col=lane&15, row=quad*4+reg)
    for (int m = 0; m < 4; ++m)
      for (int n = 0; n < 2; ++n)
        for (int r = 0; r < 4; ++r) {
          float v = fmaxf(acc[m][n][r] + bias1[n], 0.f);
          ldsH2[(m * 16 + q * 4 + r) * LD + (col0 + n * 16 + l16)] = f2bf(v);
        }
    __syncthreads();   // S1: h2 visible; also protects ldsP reuse vs prev store

    for (int m = 0; m < 4; ++m) for (int n = 0; n < 2; ++n) acc[m][n] = zero;

    // GEMM2 from LDS
    #pragma unroll
    for (int kk = 0; kk < 4; ++kk) {
      bf16x8 aF[4];
      #pragma unroll
      for (int m = 0; m < 4; ++m)
        aF[m] = *reinterpret_cast<const bf16x8*>(&ldsH2[(m * 16 + l16) * LD + kk * 32 + q * 8]);
      #pragma unroll
      for (int m = 0; m < 4; ++m)
        #pragma unroll
        for (int n = 0; n < 2; ++n)
          acc[m][n] = __builtin_amdgcn_mfma_f32_16x16x32_bf16(aF[m], bw2[n][kk], acc[m][n], 0, 0, 0);
    }

    // Epilogue: relu+bias, accumulate BN stats in registers, pack bf16 -> ldsP.
    for (int m = 0; m < 4; ++m)
      for (int n = 0; n < 2; ++n) {
        int col = col0 + n * 16 + l16;
        for (int r = 0; r < 4; ++r) {
          int rl = m * 16 + q * 4 + r;
          float v = fmaxf(acc[m][n][r] + bias2[n], 0.f);
          ldsP[rl * LD + col] = f2bf(v);
          if (row0 + rl < nrows) { fs[n] += v; fs2[n] += v * v; }
        }
      }
    __syncthreads();   // S2: pack visible; also protects ldsH2 reuse vs next h2

    // Coalesced bf16 store of the tile back to hb (in-place over agg rows).
    for (int it = 0; it < 4; ++it) {
      int idx = it * 2048 + tid * 8;
      int r = idx >> 7, c = idx & 127;
      int row = row0 + r;
      if (row < nrows)
        *reinterpret_cast<uint4*>(hb + (long long)row * DD + c) =
            *reinterpret_cast<const uint4*>(&ldsP[r * LD + c]);
    }
  }

  // per-block partial store (non-atomic)
  for (int off = 16; off < 64; off <<= 1)
    for (int n = 0; n < 2; ++n) {
      fs[n]  += __shfl_xor(fs[n], off);
      fs2[n] += __shfl_xor(fs2[n], off);
    }
  if (q == 0) {
    float* pb = partial + (long long)blockIdx.x * 256;
    for (int n = 0; n < 2; ++n) {
      int col = col0 + n * 16 + l16;
      pb[col]       = fs[n];
      pb[128 + col] = fs2[n];
    }
  }
}

// Reduce per-block partials -> scale/shift. 128 blocks: block c owns cols (c, 128+c).
__global__ __launch_bounds__(256) void k_stats(const float* __restrict__ partial,
                                               const float* __restrict__ gamma,
                                               const float* __restrict__ beta,
                                               float* __restrict__ scsh, int nrows) {
  __shared__ float s0[256], s1[256];
  int c = blockIdx.x;   // 0..127
  int t = threadIdx.x;
  float a = 0.f, b = 0.f;
  for (int r = t; r < GRID_MLP; r += 256) {
    a += partial[(long long)r * 256 + c];
    b += partial[(long long)r * 256 + 128 + c];
  }
  s0[t] = a; s1[t] = b;
  __syncthreads();
  for (int off = 128; off; off >>= 1) {
    if (t < off) { s0[t] += s0[t + off]; s1[t] += s1[t + off]; }
    __syncthreads();
  }
  if (t == 0) {
    float mean = s0[0] / (float)nrows;
    float var  = fmaxf(s1[0] / (float)nrows - mean * mean, 0.f);
    float inv  = rsqrtf(var + 1e-5f);
    float sc   = gamma[c] * inv;
    scsh[c]       = sc;
    scsh[128 + c] = beta[c] - mean * sc;
  }
}

// BN apply: read bf16 hbuf (L3-warm), write fp32 out. One thread per 8 elems.
__global__ __launch_bounds__(256) void k_bn(const unsigned short* __restrict__ hbuf,
                                            float* __restrict__ out,
                                            const float* __restrict__ scsh,
                                            long long total8) {
  long long t = (long long)blockIdx.x * 256 + threadIdx.x;
  if (t >= total8) return;
  int c0 = (int)((t * 8) & 127);
  float4 sa = *reinterpret_cast<const float4*>(scsh + c0);
  float4 sb = *reinterpret_cast<const float4*>(scsh + c0 + 4);
  float4 ha = *reinterpret_cast<const float4*>(scsh + 128 + c0);
  float4 hb = *reinterpret_cast<const float4*>(scsh + 132 + c0);
  uint4 u = *reinterpret_cast<const uint4*>(hbuf + t * 8);
  float4 a, b;
  a.x = bf2f((unsigned short)(u.x & 0xFFFF)) * sa.x + ha.x;
  a.y = bf2f((unsigned short)(u.x >> 16))    * sa.y + ha.y;
  a.z = bf2f((unsigned short)(u.y & 0xFFFF)) * sa.z + ha.z;
  a.w = bf2f((unsigned short)(u.y >> 16))    * sa.w + ha.w;
  b.x = bf2f((unsigned short)(u.z & 0xFFFF)) * sb.x + hb.x;
  b.y = bf2f((unsigned short)(u.z >> 16))    * sb.y + hb.y;
  b.z = bf2f((unsigned short)(u.w & 0xFFFF)) * sb.z + hb.z;
  b.w = bf2f((unsigned short)(u.w >> 16))    * sb.w + hb.w;
  float* of = out + t * 8;
  *reinterpret_cast<float4*>(of)     = a;
  *reinterpret_cast<float4*>(of + 4) = b;
}

extern "C" void kernel_launch(void* const* d_in, const int* in_sizes, int n_in,
                              void* d_out, int out_size, void* d_ws, size_t ws_size,
                              hipStream_t stream) {
  const float* feat  = (const float*)d_in[0];
  const int*   eidx  = (const int*)d_in[1];
  const float* w1    = (const float*)d_in[2];
  const float* b1    = (const float*)d_in[3];
  const float* w2    = (const float*)d_in[4];
  const float* b2    = (const float*)d_in[5];
  const float* gamma = (const float*)d_in[6];
  const float* beta  = (const float*)d_in[7];
  float* out = (float*)d_out;

  const int nrows  = in_sizes[0] / DD;       // 100000
  const int ne     = in_sizes[1] / 2;        // 400000
  const int ntiles = (nrows + TM - 1) / TM;  // 1563

  // ws layout (4B words), featbf + hbuf last (16B-aligned by construction):
  int* base = (int*)d_ws;
  unsigned short* wbf1 = (unsigned short*)base;            // 16384 bf16
  unsigned short* wbf2 = (unsigned short*)(base + 8192);   // 16384 bf16
  float* scsh  = (float*)(base + 16384);                   // 256
  int*   ofs   = base + 16384 + 256;                       // nrows+1
  int*   cur   = ofs + (nrows + 1);
  int*   csr   = cur + nrows;
  float* partial = (float*)(csr + ne);                     // GRID_MLP*256 (1 MB)
  int*   cnt   = (int*)(partial + (size_t)GRID_MLP * 256); // nrows
  long long w_off = (long long)(cnt + nrows - base);
  w_off = (w_off + 3) & ~3LL;                              // 16B align
  unsigned short* featbf = (unsigned short*)(base + w_off);       // nrows*DD bf16 (25.6 MB)
  unsigned short* hbuf   = featbf + (long long)nrows * DD;        // nrows*DD bf16 (25.6 MB)

  const long long total8 = (long long)nrows * DD / 8;      // 1.6M
  const int agg_blocks  = (nrows * 16 + 255) / 256;        // 6250

  k_init <<<2048,                         256, 0, stream>>>(w1, w2, feat, wbf1, wbf2,
                                                            featbf, cnt, nrows);
  k_hist <<<(ne + 255) / 256,             256, 0, stream>>>(eidx, cnt, ne);
  k_scan <<<SB,                           256, 0, stream>>>(cnt, ofs, cur, nrows);
  k_fill <<<(ne + 255) / 256,             256, 0, stream>>>(eidx, cur, csr, ne);
  k_agg  <<<agg_blocks,                   256, 0, stream>>>(featbf, ofs, csr, hbuf, nrows);
  k_mlp  <<<GRID_MLP,                     256, 0, stream>>>(hbuf, wbf1, b1, wbf2, b2,
                                                            partial, nrows, ntiles);
  k_stats<<<128,                          256, 0, stream>>>(partial, gamma, beta, scsh, nrows);
  k_bn   <<<(int)((total8 + 255) / 256),  256, 0, stream>>>(hbuf, out, scsh, total8);
}

// Round 14
// 230.283 us; speedup vs baseline: 1.0395x; 1.0347x over previous
//
#include <hip/hip_runtime.h>
#include <hip/hip_bf16.h>

#define DD 128
#define TM 64
#define LD 136        // padded LDS row stride (bf16 elems)
#define SB 128        // scan blocks
#define GRID_MLP 1024 // 4 blocks/CU persistent

typedef short bf16x8 __attribute__((ext_vector_type(8)));
typedef float f32x4  __attribute__((ext_vector_type(4)));

__device__ __forceinline__ unsigned short f2bf(float f) {
  unsigned int u = __float_as_uint(f);
  u += 0x7FFFu + ((u >> 16) & 1u);   // RNE
  return (unsigned short)(u >> 16);
}
__device__ __forceinline__ unsigned int pack2(float lo, float hi) {
  return (unsigned int)f2bf(lo) | ((unsigned int)f2bf(hi) << 16);
}
__device__ __forceinline__ float bf2f(unsigned short u) {
  union { unsigned int i; float f; } x; x.i = ((unsigned int)u) << 16; return x.f;
}
// unpack one dword (2 bf16) to two fp32 and add into a[2]
__device__ __forceinline__ void add2(float* a, unsigned int w) {
  union { unsigned int i; float f; } lo, hi;
  lo.i = w << 16; hi.i = w & 0xFFFF0000u;
  a[0] += lo.f; a[1] += hi.f;
}

// init: zero cnt, convert weights AND features fp32->bf16. One dispatch.
__global__ __launch_bounds__(256) void k_init(const float* __restrict__ w1,
                                              const float* __restrict__ w2,
                                              const float* __restrict__ feat,
                                              unsigned short* __restrict__ wbf1,
                                              unsigned short* __restrict__ wbf2,
                                              unsigned short* __restrict__ featbf,
                                              int* __restrict__ cnt, int nrows) {
  int i0 = blockIdx.x * 256 + threadIdx.x;
  int GT = gridDim.x * 256;
  for (int i = i0; i < nrows; i += GT) cnt[i] = 0;
  for (int i = i0; i < DD * DD; i += GT) { wbf1[i] = f2bf(w1[i]); wbf2[i] = f2bf(w2[i]); }
  int total8 = nrows * 16;   // 8 elems per thread
  for (int i = i0; i < total8; i += GT) {
    const float* fp = feat + (long long)i * 8;
    float4 a = *reinterpret_cast<const float4*>(fp);
    float4 b = *reinterpret_cast<const float4*>(fp + 4);
    uint4 u;
    u.x = pack2(a.x, a.y); u.y = pack2(a.z, a.w);
    u.z = pack2(b.x, b.y); u.w = pack2(b.z, b.w);
    *reinterpret_cast<uint4*>(featbf + (long long)i * 8) = u;
  }
}

// cnt[dst]++ per edge (int atomics, L2-resident)
__global__ __launch_bounds__(256) void k_hist(const int* __restrict__ ei, int* __restrict__ cnt,
                                              int ne) {
  int e = blockIdx.x * 256 + threadIdx.x;
  if (e < ne) atomicAdd(&cnt[ei[ne + e]], 1);
}

// scan stage 1: per-block chunk sums (balanced; R13 lesson: the merged
// single-dispatch scan's critical path = most-loaded block ≈ 8 µs > boundary)
__global__ __launch_bounds__(256) void k_scan1(const int* __restrict__ cnt,
                                               int* __restrict__ bsum, int n) {
  __shared__ int red[256];
  int b = blockIdx.x, t = threadIdx.x;
  int chunk = (n + SB - 1) / SB;
  int lo = b * chunk, hi = min(n, lo + chunk);
  int s = 0;
  for (int i = lo + t; i < hi; i += 256) s += cnt[i];
  red[t] = s;
  __syncthreads();
  for (int off = 128; off; off >>= 1) {
    if (t < off) red[t] += red[t + off];
    __syncthreads();
  }
  if (t == 0) bsum[b] = red[0];
}

// scan stage 2: each block redundantly scans bsum[SB] in LDS, then
// exclusive-scans its chunk -> ofs, cur.
__global__ __launch_bounds__(256) void k_scan3(const int* __restrict__ cnt,
                                               const int* __restrict__ bsum,
                                               int* __restrict__ ofs, int* __restrict__ cur,
                                               int n) {
  __shared__ int red[256];
  __shared__ int sbs[SB];
  int b = blockIdx.x, t = threadIdx.x;

  int ov = (t < SB) ? bsum[t] : 0;
  if (t < SB) sbs[t] = ov;
  __syncthreads();
  for (int off = 1; off < SB; off <<= 1) {
    int v = (t < SB && t >= off) ? sbs[t - off] : 0;
    __syncthreads();
    if (t < SB) sbs[t] += v;
    __syncthreads();
  }
  if (t < SB) sbs[t] -= ov;   // exclusive
  __syncthreads();
  int base = sbs[b];
  if (b == SB - 1 && t == SB - 1) ofs[n] = sbs[t] + ov;  // total

  int chunk  = (n + SB - 1) / SB;
  int tchunk = (chunk + 255) / 256;
  int blo = b * chunk, bhi = min(n, blo + chunk);
  int lo = blo + t * tchunk, hi = min(bhi, lo + tchunk);
  int s = 0;
  for (int i = lo; i < hi; ++i) s += cnt[i];
  int mine = s;
  red[t] = s;
  __syncthreads();
  for (int off = 1; off < 256; off <<= 1) {
    int v = (t >= off) ? red[t - off] : 0;
    __syncthreads();
    red[t] += v;
    __syncthreads();
  }
  int run = base + red[t] - mine;
  for (int i = lo; i < hi; ++i) {
    int c = cnt[i];
    ofs[i] = run; cur[i] = run;
    run += c;
  }
}

// csr[pos] = src, pos = cur[dst]++
__global__ __launch_bounds__(256) void k_fill(const int* __restrict__ ei, int* __restrict__ cur,
                                              int* __restrict__ csr, int ne) {
  int e = blockIdx.x * 256 + threadIdx.x;
  if (e >= ne) return;
  int pos = atomicAdd(&cur[ei[ne + e]], 1);
  csr[pos] = ei[e];
}

// Gather from bf16 features (256 B/row): h = feat[row] + sum(neighbors).
// fp32 accumulation of bf16-rounded inputs; RNE-pack to bf16 agg (== hbuf).
__global__ __launch_bounds__(256) void k_agg(
    const unsigned short* __restrict__ featbf, const int* __restrict__ ofs,
    const int* __restrict__ csr, unsigned short* __restrict__ agg, int nrows)
{
  int t = blockIdx.x * 256 + threadIdx.x;   // 16 threads per row, 8 cols each
  int row = t >> 4;
  if (row >= nrows) return;
  int c = (t & 15) * 8;

  float a[8];
  {
    uint4 u = *reinterpret_cast<const uint4*>(featbf + (long long)row * DD + c);
    union { unsigned int i; float f; } x;
    x.i = u.x << 16; a[0] = x.f;  x.i = u.x & 0xFFFF0000u; a[1] = x.f;
    x.i = u.y << 16; a[2] = x.f;  x.i = u.y & 0xFFFF0000u; a[3] = x.f;
    x.i = u.z << 16; a[4] = x.f;  x.i = u.z & 0xFFFF0000u; a[5] = x.f;
    x.i = u.w << 16; a[6] = x.f;  x.i = u.w & 0xFFFF0000u; a[7] = x.f;
  }

  int o0 = ofs[row], o1 = ofs[row + 1];
  int j = o0;
  for (; j + 4 <= o1; j += 4) {
    uint4 u0 = *reinterpret_cast<const uint4*>(featbf + (long long)csr[j]     * DD + c);
    uint4 u1 = *reinterpret_cast<const uint4*>(featbf + (long long)csr[j + 1] * DD + c);
    uint4 u2 = *reinterpret_cast<const uint4*>(featbf + (long long)csr[j + 2] * DD + c);
    uint4 u3 = *reinterpret_cast<const uint4*>(featbf + (long long)csr[j + 3] * DD + c);
    add2(a + 0, u0.x); add2(a + 2, u0.y); add2(a + 4, u0.z); add2(a + 6, u0.w);
    add2(a + 0, u1.x); add2(a + 2, u1.y); add2(a + 4, u1.z); add2(a + 6, u1.w);
    add2(a + 0, u2.x); add2(a + 2, u2.y); add2(a + 4, u2.z); add2(a + 6, u2.w);
    add2(a + 0, u3.x); add2(a + 2, u3.y); add2(a + 4, u3.z); add2(a + 6, u3.w);
  }
  for (; j < o1; ++j) {
    uint4 u0 = *reinterpret_cast<const uint4*>(featbf + (long long)csr[j] * DD + c);
    add2(a + 0, u0.x); add2(a + 2, u0.y); add2(a + 4, u0.z); add2(a + 6, u0.w);
  }

  uint4 u;
  u.x = pack2(a[0], a[1]); u.y = pack2(a[2], a[3]);
  u.z = pack2(a[4], a[5]); u.w = pack2(a[6], a[7]);
  *reinterpret_cast<uint4*>(agg + (long long)row * DD + c) = u;
}

// Persistent fused MLP (R9 base + cross-tile A-prefetch): next tile's kk=0,1
// A-fragments are loaded into registers after S2 (latency hides under the
// tile store + loop turn), so GEMM1 can start MFMAs immediately. Rows of
// tile+GRID_MLP are only ever written by this same block, later -> no hazard.
__global__ __launch_bounds__(256) void k_mlp(
    unsigned short* hb,
    const unsigned short* __restrict__ wbf1, const float* __restrict__ b1,
    const unsigned short* __restrict__ wbf2, const float* __restrict__ b2,
    float* __restrict__ partial, int nrows, int ntiles)
{
  __shared__ unsigned short ldsP[TM * LD];   // epilogue pack buffer
  __shared__ unsigned short ldsH2[TM * LD];  // h2 buffer
  const int tid  = threadIdx.x;
  const int wave = tid >> 6, lane = tid & 63;
  const int q = lane >> 4, l16 = lane & 15;
  const int col0 = wave * 32;

  bf16x8 bw1[2][4], bw2[2][4];
  float bias1[2], bias2[2];
  for (int n = 0; n < 2; ++n) {
    int jc = col0 + n * 16 + l16;
    bias1[n] = b1[jc];
    bias2[n] = b2[jc];
    for (int kk = 0; kk < 4; ++kk) {
      bw1[n][kk] = *reinterpret_cast<const bf16x8*>(wbf1 + jc * DD + kk * 32 + q * 8);
      bw2[n][kk] = *reinterpret_cast<const bf16x8*>(wbf2 + jc * DD + kk * 32 + q * 8);
    }
  }

  const bf16x8 zf = {0, 0, 0, 0, 0, 0, 0, 0};
  float fs[2] = {0.f, 0.f}, fs2[2] = {0.f, 0.f};

  // Prefetch first tile's kk=0,1 fragments (pf[m]=kk0, pf[4+m]=kk1).
  bf16x8 pf[8];
  if (blockIdx.x < ntiles) {
    int r0 = blockIdx.x * TM;
    #pragma unroll
    for (int m = 0; m < 4; ++m) {
      int row = r0 + m * 16 + l16;
      const unsigned short* p = hb + (long long)row * DD + q * 8;
      pf[m]     = (row < nrows) ? *reinterpret_cast<const bf16x8*>(p)      : zf;
      pf[4 + m] = (row < nrows) ? *reinterpret_cast<const bf16x8*>(p + 32) : zf;
    }
  }

  for (int tile = blockIdx.x; tile < ntiles; tile += GRID_MLP) {
    const int row0 = tile * TM;

    f32x4 acc[4][2];
    const f32x4 zero = {0.f, 0.f, 0.f, 0.f};
    for (int m = 0; m < 4; ++m) for (int n = 0; n < 2; ++n) acc[m][n] = zero;

    // GEMM1 kk=0,1 from prefetch registers (MFMAs start immediately).
    #pragma unroll
    for (int m = 0; m < 4; ++m)
      #pragma unroll
      for (int n = 0; n < 2; ++n) {
        acc[m][n] = __builtin_amdgcn_mfma_f32_16x16x32_bf16(pf[m],     bw1[n][0], acc[m][n], 0, 0, 0);
        acc[m][n] = __builtin_amdgcn_mfma_f32_16x16x32_bf16(pf[4 + m], bw1[n][1], acc[m][n], 0, 0, 0);
      }

    // GEMM1 kk=2,3 direct from global.
    #pragma unroll
    for (int kk = 2; kk < 4; ++kk) {
      bf16x8 aF[4];
      #pragma unroll
      for (int m = 0; m < 4; ++m) {
        int row = row0 + m * 16 + l16;
        aF[m] = (row < nrows)
            ? *reinterpret_cast<const bf16x8*>(hb + (long long)row * DD + kk * 32 + q * 8)
            : zf;
      }
      #pragma unroll
      for (int m = 0; m < 4; ++m)
        #pragma unroll
        for (int n = 0; n < 2; ++n)
          acc[m][n] = __builtin_amdgcn_mfma_f32_16x16x32_bf16(aF[m], bw1[n][kk], acc[m][n], 0, 0, 0);
    }

    // h2 = relu(acc + b1) -> ldsH2 (C/D: col=lane&15, row=quad*4+reg)
    for (int m = 0; m < 4; ++m)
      for (int n = 0; n < 2; ++n)
        for (int r = 0; r < 4; ++r) {
          float v = fmaxf(acc[m][n][r] + bias1[n], 0.f);
          ldsH2[(m * 16 + q * 4 + r) * LD + (col0 + n * 16 + l16)] = f2bf(v);
        }
    __syncthreads();   // S1: h2 visible; also protects ldsP reuse vs prev store

    for (int m = 0; m < 4; ++m) for (int n = 0; n < 2; ++n) acc[m][n] = zero;

    // GEMM2 from LDS
    #pragma unroll
    for (int kk = 0; kk < 4; ++kk) {
      bf16x8 aF[4];
      #pragma unroll
      for (int m = 0; m < 4; ++m)
        aF[m] = *reinterpret_cast<const bf16x8*>(&ldsH2[(m * 16 + l16) * LD + kk * 32 + q * 8]);
      #pragma unroll
      for (int m = 0; m < 4; ++m)
        #pragma unroll
        for (int n = 0; n < 2; ++n)
          acc[m][n] = __builtin_amdgcn_mfma_f32_16x16x32_bf16(aF[m], bw2[n][kk], acc[m][n], 0, 0, 0);
    }

    // Epilogue: relu+bias, accumulate BN stats in registers, pack bf16 -> ldsP.
    for (int m = 0; m < 4; ++m)
      for (int n = 0; n < 2; ++n) {
        int col = col0 + n * 16 + l16;
        for (int r = 0; r < 4; ++r) {
          int rl = m * 16 + q * 4 + r;
          float v = fmaxf(acc[m][n][r] + bias2[n], 0.f);
          ldsP[rl * LD + col] = f2bf(v);
          if (row0 + rl < nrows) { fs[n] += v; fs2[n] += v * v; }
        }
      }
    __syncthreads();   // S2: pack visible; also protects ldsH2 reuse vs next h2

    // Prefetch next tile's kk=0,1 fragments; latency hides under the store.
    int nt = tile + GRID_MLP;
    if (nt < ntiles) {
      int r0 = nt * TM;
      #pragma unroll
      for (int m = 0; m < 4; ++m) {
        int row = r0 + m * 16 + l16;
        const unsigned short* p = hb + (long long)row * DD + q * 8;
        pf[m]     = (row < nrows) ? *reinterpret_cast<const bf16x8*>(p)      : zf;
        pf[4 + m] = (row < nrows) ? *reinterpret_cast<const bf16x8*>(p + 32) : zf;
      }
    }

    // Coalesced bf16 store of the tile back to hb (in-place over agg rows).
    for (int it = 0; it < 4; ++it) {
      int idx = it * 2048 + tid * 8;
      int r = idx >> 7, c = idx & 127;
      int row = row0 + r;
      if (row < nrows)
        *reinterpret_cast<uint4*>(hb + (long long)row * DD + c) =
            *reinterpret_cast<const uint4*>(&ldsP[r * LD + c]);
    }
  }

  // per-block partial store (non-atomic)
  for (int off = 16; off < 64; off <<= 1)
    for (int n = 0; n < 2; ++n) {
      fs[n]  += __shfl_xor(fs[n], off);
      fs2[n] += __shfl_xor(fs2[n], off);
    }
  if (q == 0) {
    float* pb = partial + (long long)blockIdx.x * 256;
    for (int n = 0; n < 2; ++n) {
      int col = col0 + n * 16 + l16;
      pb[col]       = fs[n];
      pb[128 + col] = fs2[n];
    }
  }
}

// Reduce per-block partials -> scale/shift. 128 blocks: block c owns cols (c, 128+c).
__global__ __launch_bounds__(256) void k_stats(const float* __restrict__ partial,
                                               const float* __restrict__ gamma,
                                               const float* __restrict__ beta,
                                               float* __restrict__ scsh, int nrows) {
  __shared__ float s0[256], s1[256];
  int c = blockIdx.x;   // 0..127
  int t = threadIdx.x;
  float a = 0.f, b = 0.f;
  for (int r = t; r < GRID_MLP; r += 256) {
    a += partial[(long long)r * 256 + c];
    b += partial[(long long)r * 256 + 128 + c];
  }
  s0[t] = a; s1[t] = b;
  __syncthreads();
  for (int off = 128; off; off >>= 1) {
    if (t < off) { s0[t] += s0[t + off]; s1[t] += s1[t + off]; }
    __syncthreads();
  }
  if (t == 0) {
    float mean = s0[0] / (float)nrows;
    float var  = fmaxf(s1[0] / (float)nrows - mean * mean, 0.f);
    float inv  = rsqrtf(var + 1e-5f);
    float sc   = gamma[c] * inv;
    scsh[c]       = sc;
    scsh[128 + c] = beta[c] - mean * sc;
  }
}

// BN apply: read bf16 hbuf (L3-warm), write fp32 out. One thread per 8 elems.
__global__ __launch_bounds__(256) void k_bn(const unsigned short* __restrict__ hbuf,
                                            float* __restrict__ out,
                                            const float* __restrict__ scsh,
                                            long long total8) {
  long long t = (long long)blockIdx.x * 256 + threadIdx.x;
  if (t >= total8) return;
  int c0 = (int)((t * 8) & 127);
  float4 sa = *reinterpret_cast<const float4*>(scsh + c0);
  float4 sb = *reinterpret_cast<const float4*>(scsh + c0 + 4);
  float4 ha = *reinterpret_cast<const float4*>(scsh + 128 + c0);
  float4 hb = *reinterpret_cast<const float4*>(scsh + 132 + c0);
  uint4 u = *reinterpret_cast<const uint4*>(hbuf + t * 8);
  float4 a, b;
  a.x = bf2f((unsigned short)(u.x & 0xFFFF)) * sa.x + ha.x;
  a.y = bf2f((unsigned short)(u.x >> 16))    * sa.y + ha.y;
  a.z = bf2f((unsigned short)(u.y & 0xFFFF)) * sa.z + ha.z;
  a.w = bf2f((unsigned short)(u.y >> 16))    * sa.w + ha.w;
  b.x = bf2f((unsigned short)(u.z & 0xFFFF)) * sb.x + hb.x;
  b.y = bf2f((unsigned short)(u.z >> 16))    * sb.y + hb.y;
  b.z = bf2f((unsigned short)(u.w & 0xFFFF)) * sb.z + hb.z;
  b.w = bf2f((unsigned short)(u.w >> 16))    * sb.w + hb.w;
  float* of = out + t * 8;
  *reinterpret_cast<float4*>(of)     = a;
  *reinterpret_cast<float4*>(of + 4) = b;
}

extern "C" void kernel_launch(void* const* d_in, const int* in_sizes, int n_in,
                              void* d_out, int out_size, void* d_ws, size_t ws_size,
                              hipStream_t stream) {
  const float* feat  = (const float*)d_in[0];
  const int*   eidx  = (const int*)d_in[1];
  const float* w1    = (const float*)d_in[2];
  const float* b1    = (const float*)d_in[3];
  const float* w2    = (const float*)d_in[4];
  const float* b2    = (const float*)d_in[5];
  const float* gamma = (const float*)d_in[6];
  const float* beta  = (const float*)d_in[7];
  float* out = (float*)d_out;

  const int nrows  = in_sizes[0] / DD;       // 100000
  const int ne     = in_sizes[1] / 2;        // 400000
  const int ntiles = (nrows + TM - 1) / TM;  // 1563

  // ws layout (4B words), featbf + hbuf last (16B-aligned by construction):
  int* base = (int*)d_ws;
  unsigned short* wbf1 = (unsigned short*)base;            // 16384 bf16
  unsigned short* wbf2 = (unsigned short*)(base + 8192);   // 16384 bf16
  float* scsh  = (float*)(base + 16384);                   // 256
  int*   ofs   = base + 16384 + 256;                       // nrows+1
  int*   cur   = ofs + (nrows + 1);
  int*   csr   = cur + nrows;
  int*   bsum  = csr + ne;                                 // SB
  float* partial = (float*)(bsum + SB);                    // GRID_MLP*256 (1 MB)
  int*   cnt   = (int*)(partial + (size_t)GRID_MLP * 256); // nrows
  long long w_off = (long long)(cnt + nrows - base);
  w_off = (w_off + 3) & ~3LL;                              // 16B align
  unsigned short* featbf = (unsigned short*)(base + w_off);       // nrows*DD bf16 (25.6 MB)
  unsigned short* hbuf   = featbf + (long long)nrows * DD;        // nrows*DD bf16 (25.6 MB)

  const long long total8 = (long long)nrows * DD / 8;      // 1.6M
  const int agg_blocks  = (nrows * 16 + 255) / 256;        // 6250

  k_init <<<2048,                         256, 0, stream>>>(w1, w2, feat, wbf1, wbf2,
                                                            featbf, cnt, nrows);
  k_hist <<<(ne + 255) / 256,             256, 0, stream>>>(eidx, cnt, ne);
  k_scan1<<<SB,                           256, 0, stream>>>(cnt, bsum, nrows);
  k_scan3<<<SB,                           256, 0, stream>>>(cnt, bsum, ofs, cur, nrows);
  k_fill <<<(ne + 255) / 256,             256, 0, stream>>>(eidx, cur, csr, ne);
  k_agg  <<<agg_blocks,                   256, 0, stream>>>(featbf, ofs, csr, hbuf, nrows);
  k_mlp  <<<GRID_MLP,                     256, 0, stream>>>(hbuf, wbf1, b1, wbf2, b2,
                                                            partial, nrows, ntiles);
  k_stats<<<128,                          256, 0, stream>>>(partial, gamma, beta, scsh, nrows);
  k_bn   <<<(int)((total8 + 255) / 256),  256, 0, stream>>>(hbuf, out, scsh, total8);
}